// Round 6
// baseline (114.847 us; speedup 1.0000x reference)
//
#include <hip/hip_runtime.h>

#define B_SZ 16384
#define D_SZ 256
#define C_SZ 2000
#define C_PAD 2048
#define MARGIN_F 1.0f
#define NBLK 1024

typedef float floatx16 __attribute__((ext_vector_type(16)));

__device__ inline void gld_lds16(const void* g, void* l) {
  __builtin_amdgcn_global_load_lds(
      (const __attribute__((address_space(1))) void*)g,
      (__attribute__((address_space(3))) void*)l, 16, 0, 0);
}

// fp8 frag-major layout (verified prior session R11-R14):
//   chunk(tile32, ks, lane) -> 8 fp8 bytes at base + ((tile*16 + ks)*64 + lane)*8
//   lane holds M[tile*32 + (lane&31)][ks*16 + (lane>>5)*8 + j], j=0..7
// Session ledger:
//   R1-R3: __launch_bounds__(256,4) coerced 64-reg tier -> 90 MB scratch spill.
//   R4 (BEST, 92.8): hint removed, one-rowtile-per-pass GEMM.
//   R5 (95.0): 2-rowtile ILP variant -> slightly WORSE; reverted.
//   R6: ABLATION — R4 kernels unchanged, GEMM launched 2x (1st into scratch)
//       to directly measure warm-GEMM cost. dur delta vs 92.8 = GEMM + launch.

__device__ inline int2 pack8_fp8(const float* v) {
  int lo = __builtin_amdgcn_cvt_pk_fp8_f32(v[0], v[1], 0, false);
  lo = __builtin_amdgcn_cvt_pk_fp8_f32(v[2], v[3], lo, true);
  int hi = __builtin_amdgcn_cvt_pk_fp8_f32(v[4], v[5], 0, false);
  hi = __builtin_amdgcn_cvt_pk_fp8_f32(v[6], v[7], hi, true);
  return make_int2(lo, hi);
}
__device__ inline float rt_fp8(float x) {   // round-trip through fp8 e4m3
  int p = __builtin_amdgcn_cvt_pk_fp8_f32(x, x, 0, false);
  return __builtin_amdgcn_cvt_f32_fp8(p, 0);
}
__device__ inline void unpack4_fp8(int w, float* o) {  // literal selectors only
  o[0] = __builtin_amdgcn_cvt_f32_fp8(w, 0);
  o[1] = __builtin_amdgcn_cvt_f32_fp8(w, 1);
  o[2] = __builtin_amdgcn_cvt_f32_fp8(w, 2);
  o[3] = __builtin_amdgcn_cvt_f32_fp8(w, 3);
}

// ---- kernel 1: sig (D x C) fp32 -> sigq frag-major fp8; zero out[0] ----
__global__ __launch_bounds__(256) void sigq_kernel(
    const float* __restrict__ sig, char* __restrict__ sigq,
    float* __restrict__ out) {
  int t = blockIdx.x * 256 + threadIdx.x;   // 65536 chunks of 8 B
  if (t == 0) out[0] = 0.f;
  int ln = t & 63, ks = (t >> 6) & 15, ct = t >> 10;
  int col = ct * 32 + (ln & 31);
  int kb = ks * 16 + (ln >> 5) * 8;
  float v[8];
#pragma unroll
  for (int j = 0; j < 8; j++)
    v[j] = (col < C_SZ) ? sig[(size_t)(kb + j) * C_SZ + col] : 0.f;
  *(int2*)(sigq + (size_t)t * 8) = pack8_fp8(v);
}

// ---- kernel 2: prep — unchanged (verified) ----
__global__ __launch_bounds__(256) void prep_kernel(
    const float* __restrict__ pred, const char* __restrict__ sigq,
    const int* __restrict__ label, char* __restrict__ predq,
    float* __restrict__ gt) {
  __shared__ float ldsP[16][260];
  int bid = (int)blockIdx.x;
  int tid = threadIdx.x;
  int lane = tid & 63;
  int w = tid >> 6;
  int tile = bid >> 1;
  int rhi = (bid & 1) * 16;
#pragma unroll
  for (int it = 0; it < 4; it++) {
    int idx = it * 1024 + tid * 4;
    int r = idx >> 8, c = idx & 255;
    *(float4*)&ldsP[r][c] = *(const float4*)(pred + (size_t)(bid * 16 + r) * D_SZ + c);
  }
  __syncthreads();
#pragma unroll
  for (int it = 0; it < 2; it++) {
    int ch = it * 256 + tid;
    int ri = ch & 15;
    int ks = (ch >> 4) & 15;
    int khh = ch >> 8;
    int kb = ks * 16 + khh * 8;
    int ln = khh * 32 + rhi + ri;
    float v[8];
#pragma unroll
    for (int j = 0; j < 8; j++) v[j] = ldsP[ri][kb + j];
    *(int2*)(predq + ((size_t)(tile * 16 + ks) * 64 + ln) * 8) = pack8_fp8(v);
  }
  int l = lane & 31;
  int half = lane >> 5;
#pragma unroll
  for (int it = 0; it < 2; it++) {
    int r = w * 4 + it * 2 + half;
    int row = bid * 16 + r;
    int lbl = label[row];
    int ltile = lbl >> 5, l5 = lbl & 31;
    int ks = l >> 1, khh = l & 1;
    int2 p8 = *(const int2*)(sigq +
        (((size_t)(ltile * 16 + ks) * 64) + khh * 32 + l5) * 8);
    float sv[8];
    unpack4_fp8(p8.x, sv);
    unpack4_fp8(p8.y, sv + 4);
    float s = 0.f;
#pragma unroll
    for (int j = 0; j < 8; j++)
      s += rt_fp8(ldsP[r][l * 8 + j]) * sv[j];
#pragma unroll
    for (int off = 16; off > 0; off >>= 1) s += __shfl_down(s, off, 32);
    if (l == 0) gt[row] = s;
  }
}

// ---- kernel 3: GEMM + hinge (fp8 x16 MFMA) — EXACT R4 version ----
__global__ __launch_bounds__(256) void mfma_fused_kernel(
    const char* __restrict__ predq, const char* __restrict__ sigq,
    const float* __restrict__ gt, float* __restrict__ out) {
  __shared__ char Bs[4096 * 8];   // 32 KB
  __shared__ float gtl[256];      // 1 KB: gt for this block's 256 rows
  __shared__ float red[4];
  int tid = threadIdx.x;
  int lane = tid & 63;
  int w = tid >> 6;
  int kh = lane >> 5, lm = lane & 31;
  int bid = (int)blockIdx.x;
  int i = bid >> 3;
  int rsb = (bid & 7) * 8 + (i & 7);   // row superblock 0..63 (256 rows)
  int cg = i >> 3;                     // colgroup 0..15 (128 cols)

  // stage B tile (128 cols x 256 K fp8 = 32 KB), straight frag-major copy
#pragma unroll
  for (int s = 0; s < 8; s++) {
    int q0 = s * 256 + w * 64;         // 16 B chunk id, 0..2047
    gld_lds16(sigq + ((size_t)cg * 2048 + q0 + lane) * 16, (void*)(Bs + (size_t)q0 * 16));
  }
  // stage gt slice: 256 floats = 64 lanes x 16 B, wave 0 only
  if (w == 0)
    gld_lds16((const char*)gt + (size_t)rsb * 1024 + (size_t)lane * 16, (void*)gtl);

  // pass-0 A frags issued BEFORE the barrier (global, no LDS dependency)
  const char* abase0 = predq + (size_t)(rsb * 8 + w * 2) * 8192 + (size_t)lane * 8;
  long afr[16];
#pragma unroll
  for (int ks = 0; ks < 16; ks++)
    afr[ks] = *(const long*)(abase0 + (size_t)ks * 512);
  __syncthreads();

  float sum = 0.f;
#pragma unroll
  for (int rt = 0; rt < 2; rt++) {
    if (rt == 1) {
      const char* abase1 = abase0 + 8192;
#pragma unroll
      for (int ks = 0; ks < 16; ks++)
        afr[ks] = *(const long*)(abase1 + (size_t)ks * 512);
    }
#pragma unroll
    for (int ct = 0; ct < 4; ct++) {
      floatx16 acc = {};
      const char* bbase = Bs + (size_t)ct * 8192 + (size_t)lane * 8;
#pragma unroll
      for (int ks = 0; ks < 16; ks++) {
        long b = *(const long*)(bbase + (size_t)ks * 512);
        acc = __builtin_amdgcn_mfma_f32_32x32x16_fp8_fp8(afr[ks], b, acc, 0, 0, 0);
      }
      int col = cg * 128 + ct * 32 + lm;
      float keep = (col < C_SZ) ? 1.f : 0.f;   // padded cols: s=0 but hinge!=0
#pragma unroll
      for (int reg = 0; reg < 16; reg++) {
        int rl = (reg & 3) + 8 * (reg >> 2) + 4 * kh;  // C/D row map (verified)
        float mg = MARGIN_F - gtl[w * 64 + rt * 32 + rl];  // broadcast ds_read
        sum += keep * fmaxf(acc[reg] + mg, 0.f);
      }
    }
  }
#pragma unroll
  for (int off = 32; off > 0; off >>= 1) sum += __shfl_down(sum, off, 64);
  if (lane == 0) red[w] = sum;
  __syncthreads();
  // per-block share of the label-column constant: B_SZ*MARGIN / NBLK = 16
  if (tid == 0)
    atomicAdd(out, red[0] + red[1] + red[2] + red[3]
                   - (float)B_SZ * MARGIN_F / (float)NBLK);
}

extern "C" void kernel_launch(void* const* d_in, const int* in_sizes, int n_in,
                              void* d_out, int out_size, void* d_ws, size_t ws_size,
                              hipStream_t stream) {
  const float* pred  = (const float*)d_in[0];   // (B, D) fp32
  const int*   label = (const int*)d_in[1];     // (B,)
  // d_in[2] = train_classes = arange(C), unused
  const float* sig   = (const float*)d_in[3];   // (D, C) fp32
  float* out = (float*)d_out;

  float* gt    = (float*)d_ws;                                   // 64 KB
  float* dummy = (float*)((char*)d_ws + (96 << 10));             // scratch out
  char*  predq = (char*)d_ws + (128 << 10);                      // 4 MB
  char*  sigq  = (char*)d_ws + (128 << 10) + (4 << 20);          // 512 KB

  sigq_kernel<<<256, 256, 0, stream>>>(sig, sigq, out);
  prep_kernel<<<1024, 256, 0, stream>>>(pred, sigq, label, predq, gt);
  // ABLATION (R6): duplicate GEMM into scratch to isolate its cost.
  mfma_fused_kernel<<<NBLK, 256, 0, stream>>>(predq, sigq, gt, dummy);
  mfma_fused_kernel<<<NBLK, 256, 0, stream>>>(predq, sigq, gt, out);
}

// Round 7
// 107.386 us; speedup vs baseline: 1.0695x; 1.0695x over previous
//
#include <hip/hip_runtime.h>

#define B_SZ 16384
#define D_SZ 256
#define C_SZ 2000
#define MARGIN_F 1.0f
#define NBLK 1024

typedef float floatx16 __attribute__((ext_vector_type(16)));

__device__ inline void gld_lds16(const void* g, void* l) {
  __builtin_amdgcn_global_load_lds(
      (const __attribute__((address_space(1))) void*)g,
      (__attribute__((address_space(3))) void*)l, 16, 0, 0);
}

// fp8 frag-major layout (verified prior session R11-R14):
//   chunk(tile32, ks, lane) -> 8 fp8 bytes at base + ((tile*16 + ks)*64 + lane)*8
//   lane holds M[tile*32 + (lane&31)][ks*16 + (lane>>5)*8 + j], j=0..7
// Session ledger:
//   R1-R3: __launch_bounds__(256,4) coerced 64-reg tier -> 90 MB scratch spill.
//   R4 (BEST, 92.8): hint removed, one-rowtile-per-pass GEMM.
//   R5 (95.0): 2-rowtile ILP -> worse; reverted.
//   R6 ABLATION: warm GEMM+launch = 22.0 us (114.8-92.8). sigq+prep+launches
//        ~= 28 us -> overhead-dominated, not BW. Fill (~43 us) is harness floor.
//   R7: 3 kernels -> 2. sigq fused into quant_kernel (prep phase C deleted);
//       gt computed IN the GEMM via label-column gather MFMA + diagonal
//       extract (bit-exact vs main loop -> label-col cancellation exact).

__device__ inline int2 pack8_fp8(const float* v) {
  int lo = __builtin_amdgcn_cvt_pk_fp8_f32(v[0], v[1], 0, false);
  lo = __builtin_amdgcn_cvt_pk_fp8_f32(v[2], v[3], lo, true);
  int hi = __builtin_amdgcn_cvt_pk_fp8_f32(v[4], v[5], 0, false);
  hi = __builtin_amdgcn_cvt_pk_fp8_f32(v[6], v[7], hi, true);
  return make_int2(lo, hi);
}

// ---- kernel 1: quant — sigq (wave 0) + predq (all waves), no phase C ----
__global__ __launch_bounds__(256) void quant_kernel(
    const float* __restrict__ pred, const float* __restrict__ sig,
    char* __restrict__ predq, char* __restrict__ sigq,
    float* __restrict__ out) {
  __shared__ float ldsP[16][260];
  int bid = (int)blockIdx.x;
  int tid = threadIdx.x;

  // phase S: sigq quantization, 64 chunks per block (wave 0 only)
  if (tid < 64) {
    int t = bid * 64 + tid;            // global chunk id 0..65535
    if (t == 0) out[0] = 0.f;
    int ln = tid;                      // t & 63
    int ks = (t >> 6) & 15, ct = t >> 10;
    int col = ct * 32 + (ln & 31);
    int kb = ks * 16 + (ln >> 5) * 8;
    float v[8];
#pragma unroll
    for (int j = 0; j < 8; j++)
      v[j] = (col < C_SZ) ? sig[(size_t)(kb + j) * C_SZ + col] : 0.f;
    *(int2*)(sigq + (size_t)t * 8) = pack8_fp8(v);
  }

  // phase A: coalesced 16-row pred tile -> LDS
#pragma unroll
  for (int it = 0; it < 4; it++) {
    int idx = it * 1024 + tid * 4;
    int r = idx >> 8, c = idx & 255;
    *(float4*)&ldsP[r][c] = *(const float4*)(pred + (size_t)(bid * 16 + r) * D_SZ + c);
  }
  __syncthreads();

  // phase B: frag-major predq (512 chunks/block)
  int tile = bid >> 1;
  int rhi = (bid & 1) * 16;
#pragma unroll
  for (int it = 0; it < 2; it++) {
    int ch = it * 256 + tid;
    int ri = ch & 15;
    int ks = (ch >> 4) & 15;
    int khh = ch >> 8;
    int kb = ks * 16 + khh * 8;
    int ln = khh * 32 + rhi + ri;
    float v[8];
#pragma unroll
    for (int j = 0; j < 8; j++) v[j] = ldsP[ri][kb + j];
    *(int2*)(predq + ((size_t)(tile * 16 + ks) * 64 + ln) * 8) = pack8_fp8(v);
  }
}

// ---- kernel 2: GEMM + in-kernel gt + hinge (fp8 x16 MFMA) ----
// block = 256 rows x 128 cols, 4 waves; wave = 64 rows (2 rowtiles) x 128.
// gt via label-column gather MFMA: lane lm gathers column label[row lm] as
// B-slot lm; D[j][j] (lane rl==lm) is row j's gt, bit-exact vs main loop.
__global__ __launch_bounds__(256) void mfma_fused_kernel(
    const char* __restrict__ predq, const char* __restrict__ sigq,
    const int* __restrict__ label, float* __restrict__ out) {
  __shared__ char Bs[4096 * 8];   // 32 KB
  __shared__ float gtl[256];      // gt for this block's 256 rows
  __shared__ float red[4];
  int tid = threadIdx.x;
  int lane = tid & 63;
  int w = tid >> 6;
  int kh = lane >> 5, lm = lane & 31;
  int bid = (int)blockIdx.x;
  int i = bid >> 3;
  int rsb = (bid & 7) * 8 + (i & 7);   // row superblock 0..63 (256 rows)
  int cg = i >> 3;                     // colgroup 0..15 (128 cols)
  // per-XCD: XCD x sees rsbs x*8..x*8+7 (512 KB predq) across all 16 cgs.

  // stage B tile (128 cols x 256 K fp8 = 32 KB), straight frag-major copy
#pragma unroll
  for (int s = 0; s < 8; s++) {
    int q0 = s * 256 + w * 64;         // 16 B chunk id, 0..2047
    gld_lds16(sigq + ((size_t)cg * 2048 + q0 + lane) * 16, (void*)(Bs + (size_t)q0 * 16));
  }

  int rowbase = rsb * 256 + w * 64;
  int lbl0 = label[rowbase + lm];        // label of row rt0,lm (bcast kh halves)
  int lbl1 = label[rowbase + 32 + lm];   // label of row rt1,lm

  const char* abase = predq + (size_t)(rsb * 8 + w * 2) * 8192 + (size_t)lane * 8;
  long afr[16];

  // ---- gt phase, rowtile 0 ----
#pragma unroll
  for (int ks = 0; ks < 16; ks++)
    afr[ks] = *(const long*)(abase + (size_t)ks * 512);
  {
    floatx16 accl = {};
    const char* cb = sigq + (size_t)(lbl0 >> 5) * 8192 + (size_t)kh * 256
                          + (size_t)(lbl0 & 31) * 8;
#pragma unroll
    for (int ks = 0; ks < 16; ks++) {
      long b = *(const long*)(cb + (size_t)ks * 512);
      accl = __builtin_amdgcn_mfma_f32_32x32x16_fp8_fp8(afr[ks], b, accl, 0, 0, 0);
    }
#pragma unroll
    for (int reg = 0; reg < 16; reg++) {
      int rl = (reg & 3) + 8 * (reg >> 2) + 4 * kh;
      if (rl == lm) gtl[w * 64 + lm] = accl[reg];   // diag D[lm][lm]
    }
  }
  // ---- gt phase, rowtile 1 (afr reused; main loop runs rt=1 first) ----
#pragma unroll
  for (int ks = 0; ks < 16; ks++)
    afr[ks] = *(const long*)(abase + 8192 + (size_t)ks * 512);
  {
    floatx16 accl = {};
    const char* cb = sigq + (size_t)(lbl1 >> 5) * 8192 + (size_t)kh * 256
                          + (size_t)(lbl1 & 31) * 8;
#pragma unroll
    for (int ks = 0; ks < 16; ks++) {
      long b = *(const long*)(cb + (size_t)ks * 512);
      accl = __builtin_amdgcn_mfma_f32_32x32x16_fp8_fp8(afr[ks], b, accl, 0, 0, 0);
    }
#pragma unroll
    for (int reg = 0; reg < 16; reg++) {
      int rl = (reg & 3) + 8 * (reg >> 2) + 4 * kh;
      if (rl == lm) gtl[w * 64 + 32 + lm] = accl[reg];
    }
  }
  __syncthreads();   // Bs staged (vmcnt drain) + gtl written

  float sum = 0.f;
#pragma unroll
  for (int p = 0; p < 2; p++) {
    int rt = 1 - p;                    // afr currently holds rowtile 1
    if (p == 1) {
#pragma unroll
      for (int ks = 0; ks < 16; ks++)
        afr[ks] = *(const long*)(abase + (size_t)ks * 512);   // L2 hits
    }
#pragma unroll
    for (int ct = 0; ct < 4; ct++) {
      floatx16 acc = {};
      const char* bbase = Bs + (size_t)ct * 8192 + (size_t)lane * 8;
#pragma unroll
      for (int ks = 0; ks < 16; ks++) {
        long b = *(const long*)(bbase + (size_t)ks * 512);
        acc = __builtin_amdgcn_mfma_f32_32x32x16_fp8_fp8(afr[ks], b, acc, 0, 0, 0);
      }
      int col = cg * 128 + ct * 32 + lm;
      float keep = (col < C_SZ) ? 1.f : 0.f;   // padded cols: s=0 but hinge!=0
#pragma unroll
      for (int reg = 0; reg < 16; reg++) {
        int rl = (reg & 3) + 8 * (reg >> 2) + 4 * kh;  // C/D row map (verified)
        float mg = MARGIN_F - gtl[w * 64 + rt * 32 + rl];
        sum += keep * fmaxf(acc[reg] + mg, 0.f);
      }
    }
  }
#pragma unroll
  for (int off = 32; off > 0; off >>= 1) sum += __shfl_down(sum, off, 64);
  if (lane == 0) red[w] = sum;
  __syncthreads();
  // label-column hinge == MARGIN exactly (bit-identical gt) -> subtract
  // per-block share of the constant: B_SZ*MARGIN / NBLK = 16
  if (tid == 0)
    atomicAdd(out, red[0] + red[1] + red[2] + red[3]
                   - (float)B_SZ * MARGIN_F / (float)NBLK);
}

extern "C" void kernel_launch(void* const* d_in, const int* in_sizes, int n_in,
                              void* d_out, int out_size, void* d_ws, size_t ws_size,
                              hipStream_t stream) {
  const float* pred  = (const float*)d_in[0];   // (B, D) fp32
  const int*   label = (const int*)d_in[1];     // (B,) int32 (x64 disabled)
  // d_in[2] = train_classes = arange(C), unused
  const float* sig   = (const float*)d_in[3];   // (D, C) fp32
  float* out = (float*)d_out;

  char* predq = (char*)d_ws + (128 << 10);                      // 4 MB
  char* sigq  = (char*)d_ws + (128 << 10) + (4 << 20);          // 512 KB

  quant_kernel<<<1024, 256, 0, stream>>>(pred, sig, predq, sigq, out);
  mfma_fused_kernel<<<NBLK, 256, 0, stream>>>(predq, sigq, label, out);
}

// Round 8
// 94.514 us; speedup vs baseline: 1.2151x; 1.1362x over previous
//
#include <hip/hip_runtime.h>

#define B_SZ 16384
#define D_SZ 256
#define C_SZ 2000
#define MARGIN_F 1.0f
#define NBLK 1024

typedef float floatx16 __attribute__((ext_vector_type(16)));

__device__ inline void gld_lds16(const void* g, void* l) {
  __builtin_amdgcn_global_load_lds(
      (const __attribute__((address_space(1))) void*)g,
      (__attribute__((address_space(3))) void*)l, 16, 0, 0);
}

// fp8 frag-major layout (verified prior session R11-R14):
//   chunk(tile32, ks, lane) -> 8 fp8 bytes at base + ((tile*16 + ks)*64 + lane)*8
//   lane holds M[tile*32 + (lane&31)][ks*16 + (lane>>5)*8 + j], j=0..7
// Session ledger:
//   R1-R3: __launch_bounds__(256,4) -> 64-reg tier coercion, 90 MB spill.
//   R4 (92.8): 3-kernel, GEMM 22 us (R6 ablation), non-GEMM ~28 us.
//   R5 (95.0): 2-rowtile ILP -> worse; GEMM not pipe-bound.
//   R7 (107.4): gt fused INTO GEMM -> 16x redundant gather per rsb (one per
//       colgroup): GEMM 42.7 us. Quant fusion side was fine (~-6 us).
//   R8: gt once-per-row in a tiny kernel (reads sigq, coalesced); quant_kernel
//       LDS-free (1 thread = 1 pred line -> 2 chunks); GEMM = exact R4.

__device__ inline int2 pack8_fp8(const float* v) {
  int lo = __builtin_amdgcn_cvt_pk_fp8_f32(v[0], v[1], 0, false);
  lo = __builtin_amdgcn_cvt_pk_fp8_f32(v[2], v[3], lo, true);
  int hi = __builtin_amdgcn_cvt_pk_fp8_f32(v[4], v[5], 0, false);
  hi = __builtin_amdgcn_cvt_pk_fp8_f32(v[6], v[7], hi, true);
  return make_int2(lo, hi);
}
__device__ inline float rt_fp8(float x) {   // round-trip through fp8 e4m3
  int p = __builtin_amdgcn_cvt_pk_fp8_f32(x, x, 0, false);
  return __builtin_amdgcn_cvt_f32_fp8(p, 0);
}
__device__ inline void unpack4_fp8(int w, float* o) {  // literal selectors only
  o[0] = __builtin_amdgcn_cvt_f32_fp8(w, 0);
  o[1] = __builtin_amdgcn_cvt_f32_fp8(w, 1);
  o[2] = __builtin_amdgcn_cvt_f32_fp8(w, 2);
  o[3] = __builtin_amdgcn_cvt_f32_fp8(w, 3);
}

// ---- kernel 1: quant — sigq (threads 0..63) + predq (all), LDS-free ----
// predq: thread owns ONE 64-B pred line (row tid&15, k-block tid>>4) and
// emits its two frag-major 8-B chunks. No LDS, no barrier, no scalar reads.
__global__ __launch_bounds__(256) void quant_kernel(
    const float* __restrict__ pred, const float* __restrict__ sig,
    char* __restrict__ predq, char* __restrict__ sigq,
    float* __restrict__ out) {
  int bid = (int)blockIdx.x;
  int tid = threadIdx.x;

  // phase S: sigq quantization, 64 chunks per block
  if (tid < 64) {
    int t = bid * 64 + tid;            // global chunk id 0..65535
    if (t == 0) out[0] = 0.f;
    int ln = tid;
    int ks = (t >> 6) & 15, ct = t >> 10;
    int col = ct * 32 + (ln & 31);     // half-wave: 32 consecutive cols ✓
    int kb = ks * 16 + (ln >> 5) * 8;
    float v[8];
#pragma unroll
    for (int j = 0; j < 8; j++)
      v[j] = (col < C_SZ) ? sig[(size_t)(kb + j) * C_SZ + col] : 0.f;
    *(int2*)(sigq + (size_t)t * 8) = pack8_fp8(v);
  }

  // phase P: predq. r = bid*16 + (tid&15), k-block ks = tid>>4.
  int ri = tid & 15;
  int ks = tid >> 4;
  int tile = bid >> 1;
  int rhi = (bid & 1) * 16;
  const float4* p = (const float4*)(pred + (size_t)(bid * 16 + ri) * D_SZ + ks * 16);
  float4 f0 = p[0], f1 = p[1], f2 = p[2], f3 = p[3];   // one full 64-B line
  float lo[8] = {f0.x, f0.y, f0.z, f0.w, f1.x, f1.y, f1.z, f1.w};
  float hi[8] = {f2.x, f2.y, f2.z, f2.w, f3.x, f3.y, f3.z, f3.w};
  size_t cbase = ((size_t)(tile * 16 + ks) * 64 + rhi + ri) * 8;
  *(int2*)(predq + cbase)           = pack8_fp8(lo);   // khh=0: ln = rhi+ri
  *(int2*)(predq + cbase + 32 * 8)  = pack8_fp8(hi);   // khh=1: ln = 32+rhi+ri
}

// ---- kernel 2: gt — once per row, R4 phase-C math (verified) ----
// 1024 blocks x 16 rows; half-wave per row; lane l owns k-oct l.
__global__ __launch_bounds__(256) void gt_kernel(
    const float* __restrict__ pred, const char* __restrict__ sigq,
    const int* __restrict__ label, float* __restrict__ gt) {
  int bid = (int)blockIdx.x;
  int tid = threadIdx.x;
  int lane = tid & 63;
  int w = tid >> 6;
  int l = lane & 31;
  int half = lane >> 5;
#pragma unroll
  for (int it = 0; it < 2; it++) {
    int r = w * 4 + it * 2 + half;    // 0..15
    int row = bid * 16 + r;
    int lbl = label[row];
    int ltile = lbl >> 5, l5 = lbl & 31;
    int ks = l >> 1, khh = l & 1;
    int2 p8 = *(const int2*)(sigq +
        (((size_t)(ltile * 16 + ks) * 64) + khh * 32 + l5) * 8);
    float sv[8];
    unpack4_fp8(p8.x, sv);
    unpack4_fp8(p8.y, sv + 4);
    const float4* pr = (const float4*)(pred + (size_t)row * D_SZ + l * 8);
    float4 a0 = pr[0], a1 = pr[1];    // 32 B, half-wave covers full row ✓
    float pv[8] = {a0.x, a0.y, a0.z, a0.w, a1.x, a1.y, a1.z, a1.w};
    float s = 0.f;
#pragma unroll
    for (int j = 0; j < 8; j++) s += rt_fp8(pv[j]) * sv[j];
#pragma unroll
    for (int off = 16; off > 0; off >>= 1) s += __shfl_down(s, off, 32);
    if (l == 0) gt[row] = s;
  }
}

// ---- kernel 3: GEMM + hinge (fp8 x16 MFMA) — EXACT R4 version ----
__global__ __launch_bounds__(256) void mfma_fused_kernel(
    const char* __restrict__ predq, const char* __restrict__ sigq,
    const float* __restrict__ gt, float* __restrict__ out) {
  __shared__ char Bs[4096 * 8];   // 32 KB
  __shared__ float gtl[256];      // 1 KB: gt for this block's 256 rows
  __shared__ float red[4];
  int tid = threadIdx.x;
  int lane = tid & 63;
  int w = tid >> 6;
  int kh = lane >> 5, lm = lane & 31;
  int bid = (int)blockIdx.x;
  int i = bid >> 3;
  int rsb = (bid & 7) * 8 + (i & 7);   // row superblock 0..63 (256 rows)
  int cg = i >> 3;                     // colgroup 0..15 (128 cols)

  // stage B tile (128 cols x 256 K fp8 = 32 KB), straight frag-major copy
#pragma unroll
  for (int s = 0; s < 8; s++) {
    int q0 = s * 256 + w * 64;         // 16 B chunk id, 0..2047
    gld_lds16(sigq + ((size_t)cg * 2048 + q0 + lane) * 16, (void*)(Bs + (size_t)q0 * 16));
  }
  // stage gt slice: 256 floats = 64 lanes x 16 B, wave 0 only
  if (w == 0)
    gld_lds16((const char*)gt + (size_t)rsb * 1024 + (size_t)lane * 16, (void*)gtl);

  // pass-0 A frags issued BEFORE the barrier (global, no LDS dependency)
  const char* abase0 = predq + (size_t)(rsb * 8 + w * 2) * 8192 + (size_t)lane * 8;
  long afr[16];
#pragma unroll
  for (int ks = 0; ks < 16; ks++)
    afr[ks] = *(const long*)(abase0 + (size_t)ks * 512);
  __syncthreads();

  float sum = 0.f;
#pragma unroll
  for (int rt = 0; rt < 2; rt++) {
    if (rt == 1) {
      const char* abase1 = abase0 + 8192;
#pragma unroll
      for (int ks = 0; ks < 16; ks++)
        afr[ks] = *(const long*)(abase1 + (size_t)ks * 512);
    }
#pragma unroll
    for (int ct = 0; ct < 4; ct++) {
      floatx16 acc = {};
      const char* bbase = Bs + (size_t)ct * 8192 + (size_t)lane * 8;
#pragma unroll
      for (int ks = 0; ks < 16; ks++) {
        long b = *(const long*)(bbase + (size_t)ks * 512);
        acc = __builtin_amdgcn_mfma_f32_32x32x16_fp8_fp8(afr[ks], b, acc, 0, 0, 0);
      }
      int col = cg * 128 + ct * 32 + lm;
      float keep = (col < C_SZ) ? 1.f : 0.f;   // padded cols: s=0 but hinge!=0
#pragma unroll
      for (int reg = 0; reg < 16; reg++) {
        int rl = (reg & 3) + 8 * (reg >> 2) + 4 * kh;  // C/D row map (verified)
        float mg = MARGIN_F - gtl[w * 64 + rt * 32 + rl];  // broadcast ds_read
        sum += keep * fmaxf(acc[reg] + mg, 0.f);
      }
    }
  }
#pragma unroll
  for (int off = 32; off > 0; off >>= 1) sum += __shfl_down(sum, off, 64);
  if (lane == 0) red[w] = sum;
  __syncthreads();
  // per-block share of the label-column constant: B_SZ*MARGIN / NBLK = 16
  if (tid == 0)
    atomicAdd(out, red[0] + red[1] + red[2] + red[3]
                   - (float)B_SZ * MARGIN_F / (float)NBLK);
}

extern "C" void kernel_launch(void* const* d_in, const int* in_sizes, int n_in,
                              void* d_out, int out_size, void* d_ws, size_t ws_size,
                              hipStream_t stream) {
  const float* pred  = (const float*)d_in[0];   // (B, D) fp32
  const int*   label = (const int*)d_in[1];     // (B,)
  // d_in[2] = train_classes = arange(C), unused
  const float* sig   = (const float*)d_in[3];   // (D, C) fp32
  float* out = (float*)d_out;

  float* gt    = (float*)d_ws;                                   // 64 KB
  char*  predq = (char*)d_ws + (128 << 10);                      // 4 MB
  char*  sigq  = (char*)d_ws + (128 << 10) + (4 << 20);          // 512 KB

  quant_kernel<<<1024, 256, 0, stream>>>(pred, sig, predq, sigq, out);
  gt_kernel<<<1024, 256, 0, stream>>>(pred, sigq, label, gt);
  mfma_fused_kernel<<<NBLK, 256, 0, stream>>>(predq, sigq, gt, out);
}